// Round 30
// baseline (250.970 us; speedup 1.0000x reference)
//
#include <hip/hip_runtime.h>

#define NN 50000
#define NE 800000
#define D 128
#define NG 128
#define NGRP 8
#define GRPSZ 6250
#define FILL_NB 392                    // 49 slices x 8 groups
#define ESL ((NE + 48) / 49)
#define CAP 64
#define GEMM_NB 391

typedef __attribute__((ext_vector_type(8))) short bf16x8;
typedef __attribute__((ext_vector_type(4))) float f32x4;
typedef __attribute__((ext_vector_type(4))) float f32x4v;
typedef __attribute__((ext_vector_type(4))) ushort u16x4;

static __device__ __forceinline__ ushort f2bf(float f) {
    uint x = __float_as_uint(f);
    x += 0x7fffu + ((x >> 16) & 1u);   // RNE
    return (ushort)(x >> 16);
}
static __device__ __forceinline__ float bf2f(ushort u) { return __uint_as_float((uint)u << 16); }
static __device__ __forceinline__ float blo16(uint u) { return __uint_as_float(u << 16); }
static __device__ __forceinline__ float bhi16(uint u) { return __uint_as_float(u & 0xffff0000u); }

// ---------------- fusedP: fill (bid 0..391) || cast_x (nontemporal) || cast_w3 ----------------
// Fill's partitioned col slices (800KB/XCD) must stay L2-resident to avoid write
// amplification; the cast role streams 38MB with zero reuse -> nontemporal so it
// doesn't evict fill's col lines.
#define CASTX_NB 3125          // NN*32/512
#define CASTW_NB 96            // 3*16384/512
__global__ __launch_bounds__(512) void fusedP_kernel(
    const int* __restrict__ src, const int* __restrict__ dst,
    int* __restrict__ fillp, ushort* __restrict__ colu,
    const float* __restrict__ x, ushort* __restrict__ xb,
    const float* __restrict__ Wl1, const float* __restrict__ Wr1,
    const float* __restrict__ Wl2, const float* __restrict__ Wr2,
    const float* __restrict__ Wl3, const float* __restrict__ Wr3,
    ushort* __restrict__ wlh, ushort* __restrict__ wll,
    ushort* __restrict__ wrh, ushort* __restrict__ wrl) {
    const int bid = blockIdx.x;
    if (bid < FILL_NB) {
        const int grp = bid & 7;
        const int slice = bid >> 3;
        const int dlo = grp * GRPSZ, dhi = dlo + GRPSZ;
        const int e0 = slice * ESL;
        const int e1 = min(e0 + ESL, NE);
        for (int e = e0 + (int)threadIdx.x; e < e1; e += 512) {
            int d = dst[e];
            if (d >= dlo && d < dhi) {
                int s = src[e];
                int pos = atomicAdd(&fillp[d], 1);
                if (pos < CAP) colu[d * CAP + pos] = (ushort)s;
            }
        }
    } else if (bid < FILL_NB + CASTX_NB) {
        int i = (bid - FILL_NB) * 512 + threadIdx.x;   // < NN*32
        int n = i >> 5, g = i & 31;
        f32x4v v = __builtin_nontemporal_load(
            reinterpret_cast<const f32x4v*>(x + (size_t)n * D + g * 4));
        u16x4 o;
        o.x = f2bf(v.x); o.y = f2bf(v.y); o.z = f2bf(v.z); o.w = f2bf(v.w);
        __builtin_nontemporal_store(o, reinterpret_cast<u16x4*>(xb + (size_t)n * D + g * 4));
    } else {
        int i = (bid - FILL_NB - CASTX_NB) * 512 + threadIdx.x;   // < 3*16384
        int layer = i >> 14, j = i & 16383;
        int colg = j >> 7, k = j & 127;
        const float* Wl = (layer == 0) ? Wl1 : ((layer == 1) ? Wl2 : Wl3);
        const float* Wr = (layer == 0) ? Wr1 : ((layer == 1) ? Wr2 : Wr3);
        float vl = Wl[k * 128 + colg];
        float vr = Wr[k * 128 + colg];
        ushort hl = f2bf(vl), hr = f2bf(vr);
        wlh[i] = hl; wll[i] = f2bf(vl - bf2f(hl));
        wrh[i] = hr; wrl[i] = f2bf(vr - bf2f(hr));
    }
}

// ---------------- gemm2 body (2-term split-weight bf16 MFMA) ----------------
static __device__ __forceinline__ void gemm2_body(
    char* As, int rb,
    const ushort* __restrict__ ain,
    const ushort* __restrict__ wlh, const ushort* __restrict__ wll,
    const ushort* __restrict__ wrh, const ushort* __restrict__ wrl,
    const float* __restrict__ bl,
    ushort* __restrict__ y, ushort* __restrict__ z, int N) {
    const int tid = threadIdx.x;
    const int w = tid >> 6, lane = tid & 63;
    const int row0 = rb * 128;
    const int lrow = lane & 15, lk = lane >> 4;
    const int colg = w * 16 + lrow;

    bf16x8 ylh[4], yll[4], zrh[4], zrl[4];
#pragma unroll
    for (int kb = 0; kb < 4; ++kb) {
        int off = colg * 128 + kb * 32 + lk * 8;
        ylh[kb] = *reinterpret_cast<const bf16x8*>(wlh + off);
        yll[kb] = *reinterpret_cast<const bf16x8*>(wll + off);
        zrh[kb] = *reinterpret_cast<const bf16x8*>(wrh + off);
        zrl[kb] = *reinterpret_cast<const bf16x8*>(wrl + off);
    }
    const float bias = bl[colg];

    {   // stage 32 KB; source pre-swizzled (involution, 256B rows)
        const char* gbase = (const char*)ain + (size_t)row0 * 256;
#pragma unroll
        for (int i = 0; i < 4; ++i) {
            int Ld = i * 8192 + w * 1024 + lane * 16;
            int gs = Ld ^ (((Ld >> 8) & 7) << 4);
            __builtin_amdgcn_global_load_lds(
                (const uint*)(gbase + gs),
                (uint*)(As + i * 8192 + w * 1024), 16, 0, 0);
        }
    }
    __syncthreads();

#pragma unroll
    for (int mt = 0; mt < 8; ++mt) {
        const int ar = mt * 16 + lrow;
        const int swz = (ar & 7) << 4;
        const char* ap = As + ar * 256;
        bf16x8 ah[4];
#pragma unroll
        for (int kb = 0; kb < 4; ++kb) {
            int b_ = kb * 64 + lk * 16;
            ah[kb] = *reinterpret_cast<const bf16x8*>(ap + (b_ ^ swz));
        }
        f32x4 accy = {0.f, 0.f, 0.f, 0.f}, accz = {0.f, 0.f, 0.f, 0.f};
#pragma unroll
        for (int kb = 0; kb < 4; ++kb) {
            accy = __builtin_amdgcn_mfma_f32_16x16x32_bf16(ah[kb], ylh[kb], accy, 0, 0, 0);
            accy = __builtin_amdgcn_mfma_f32_16x16x32_bf16(ah[kb], yll[kb], accy, 0, 0, 0);
            accz = __builtin_amdgcn_mfma_f32_16x16x32_bf16(ah[kb], zrh[kb], accz, 0, 0, 0);
            accz = __builtin_amdgcn_mfma_f32_16x16x32_bf16(ah[kb], zrl[kb], accz, 0, 0, 0);
        }
#pragma unroll
        for (int r = 0; r < 4; ++r) {
            int rowg = row0 + mt * 16 + lk * 4 + r;
            if (rowg < N) {
                y[(size_t)rowg * D + colg] = f2bf(accy[r]);
                z[(size_t)rowg * D + colg] = f2bf(accz[r] + bias);
            }
        }
    }
}

__global__ __launch_bounds__(512, 4) void gemm2_kernel(
    const ushort* __restrict__ ain,
    const ushort* __restrict__ wlh, const ushort* __restrict__ wll,
    const ushort* __restrict__ wrh, const ushort* __restrict__ wrl,
    const float* __restrict__ bl,
    ushort* __restrict__ y, ushort* __restrict__ z, int N) {
    __shared__ char As[128 * 256];
    gemm2_body(As, blockIdx.x, ain, wlh, wll, wrh, wrl, bl, y, z, N);
}

// ---------------- gather: h = bf16(relu(mean_gather(y) + z)), in-place over z ----------------
__global__ __launch_bounds__(256) void gather_relu(
    const ushort* __restrict__ y, ushort* __restrict__ z,
    const int* __restrict__ deg, const ushort* __restrict__ colu, int N) {
    int wid = (blockIdx.x * 256 + threadIdx.x) >> 6;
    if (wid >= N) return;
    const int lane = threadIdx.x & 63;
    const int h = lane >> 5, li = lane & 31;
    const int dg = deg[wid];
    const int lo = wid * CAP;
    const int hi = lo + min(dg, CAP);
    float a0 = 0.f, a1 = 0.f, a2 = 0.f, a3 = 0.f;
    int e = lo + h;
    for (; e + 6 < hi; e += 8) {
        int s0 = colu[e], s1 = colu[e + 2], s2 = colu[e + 4], s3 = colu[e + 6];
        uint2 v0 = *reinterpret_cast<const uint2*>(y + (size_t)s0 * D + li * 4);
        uint2 v1 = *reinterpret_cast<const uint2*>(y + (size_t)s1 * D + li * 4);
        uint2 v2 = *reinterpret_cast<const uint2*>(y + (size_t)s2 * D + li * 4);
        uint2 v3 = *reinterpret_cast<const uint2*>(y + (size_t)s3 * D + li * 4);
        a0 += (blo16(v0.x) + blo16(v1.x)) + (blo16(v2.x) + blo16(v3.x));
        a1 += (bhi16(v0.x) + bhi16(v1.x)) + (bhi16(v2.x) + bhi16(v3.x));
        a2 += (blo16(v0.y) + blo16(v1.y)) + (blo16(v2.y) + blo16(v3.y));
        a3 += (bhi16(v0.y) + bhi16(v1.y)) + (bhi16(v2.y) + bhi16(v3.y));
    }
    for (; e < hi; e += 2) {
        int s = colu[e];
        uint2 v = *reinterpret_cast<const uint2*>(y + (size_t)s * D + li * 4);
        a0 += blo16(v.x); a1 += bhi16(v.x);
        a2 += blo16(v.y); a3 += bhi16(v.y);
    }
    a0 += __shfl_xor(a0, 32, 64);
    a1 += __shfl_xor(a1, 32, 64);
    a2 += __shfl_xor(a2, 32, 64);
    a3 += __shfl_xor(a3, 32, 64);
    if (h == 0) {
        float inv = 1.0f / fmaxf((float)dg, 1.0f);
        uint2 zv = *reinterpret_cast<const uint2*>(z + (size_t)wid * D + li * 4);
        float h0 = fmaxf(a0 * inv + blo16(zv.x), 0.f);
        float h1 = fmaxf(a1 * inv + bhi16(zv.x), 0.f);
        float h2 = fmaxf(a2 * inv + blo16(zv.y), 0.f);
        float h3 = fmaxf(a3 * inv + bhi16(zv.y), 0.f);
        uint2 o;
        o.x = (uint)f2bf(h0) | ((uint)f2bf(h1) << 16);
        o.y = (uint)f2bf(h2) | ((uint)f2bf(h3) << 16);
        *reinterpret_cast<uint2*>(z + (size_t)wid * D + li * 4) = o;
    }
}

// ---------------- fused pool+head ----------------
__global__ __launch_bounds__(256) void pool_head(
    const ushort* __restrict__ hbuf, const int* __restrict__ batch, int N,
    const float* __restrict__ W1, const float* __restrict__ b1,
    const float* __restrict__ W2, const float* __restrict__ b2,
    float* __restrict__ out) {
    __shared__ float part[4][128];
    __shared__ float gl[128];
    __shared__ float tl[128];
    __shared__ float lg[10];
    __shared__ float red[2];
    const int b = blockIdx.x;
    const int tid = threadIdx.x;
    const int wv = tid >> 6, lane = tid & 63;
    const int cb = lane * 2;

    int lo = 0, r = N;
    while (lo < r) { int m = (lo + r) >> 1; if (batch[m] < b) lo = m + 1; else r = m; }
    int hi = lo; r = N;
    while (hi < r) { int m = (hi + r) >> 1; if (batch[m] < b + 1) hi = m + 1; else r = m; }

    float a0 = 0.f, a1 = 0.f;
    for (int n = lo + wv; n < hi; n += 4) {
        uint v = *reinterpret_cast<const uint*>(hbuf + (size_t)n * D + cb);
        a0 += blo16(v); a1 += bhi16(v);
    }
    part[wv][cb] = a0;
    part[wv][cb + 1] = a1;
    __syncthreads();

    const int j = tid & 127;
    if (tid < 128) {
        float c = fmaxf((float)(hi - lo), 1.0f);
        gl[j] = (part[0][j] + part[1][j] + part[2][j] + part[3][j]) / c;
    }
    __syncthreads();

    if (tid < 128) {
        float t = b1[j];
        for (int k = 0; k < 128; ++k) t += gl[k] * W1[k * 128 + j];
        tl[j] = fmaxf(t, 0.0f);
    }
    __syncthreads();

    if (tid < 10) {
        float acc = b2[tid];
        for (int k = 0; k < 128; ++k) acc += tl[k] * W2[k * 10 + tid];
        lg[tid] = acc;
    }
    __syncthreads();

    if (tid == 0) {
        float m = lg[0];
        for (int q = 1; q < 10; ++q) m = fmaxf(m, lg[q]);
        float s = 0.0f;
        for (int q = 0; q < 10; ++q) s += expf(lg[q] - m);
        red[0] = m;
        red[1] = logf(s);
    }
    __syncthreads();

    if (tid < 10) out[b * 10 + tid] = lg[tid] - red[0] - red[1];
}

extern "C" void kernel_launch(void* const* d_in, const int* in_sizes, int n_in,
                              void* d_out, int out_size, void* d_ws, size_t ws_size,
                              hipStream_t stream) {
    const float* x    = (const float*)d_in[0];
    const int*   ei   = (const int*)d_in[1];
    const int*   src  = ei;
    const int*   dst  = ei + NE;
    const int*   batch = (const int*)d_in[2];
    const float* Wl1 = (const float*)d_in[3];
    const float* bl1 = (const float*)d_in[4];
    const float* Wr1 = (const float*)d_in[5];
    const float* Wl2 = (const float*)d_in[6];
    const float* bl2 = (const float*)d_in[7];
    const float* Wr2 = (const float*)d_in[8];
    const float* Wl3 = (const float*)d_in[9];
    const float* bl3 = (const float*)d_in[10];
    const float* Wr3 = (const float*)d_in[11];
    const float* W1  = (const float*)d_in[12];
    const float* b1  = (const float*)d_in[13];
    const float* W2  = (const float*)d_in[14];
    const float* b2  = (const float*)d_in[15];
    float* out = (float*)d_out;

    char* p = (char*)d_ws;
    char* S0 = p; p += 12800000;     // x/h bf16 [N][128]
    char* S1 = p; p += 12800000;     // y bf16
    char* S2 = p; p += 12800000;     // z / h bf16 (in place)
    ushort* wlh = (ushort*)p; p += 3 * 32768;
    ushort* wll = (ushort*)p; p += 3 * 32768;
    ushort* wrh = (ushort*)p; p += 3 * 32768;
    ushort* wrl = (ushort*)p; p += 3 * 32768;
    int* fillp   = (int*)p;   p += 200000;
    ushort* colu = (ushort*)p; p += NN * CAP * 2;   // 6.4 MB
    // ~46 MB total

    hipMemsetAsync(fillp, 0, (size_t)NN * 4, stream);

    // ---- fusedP: fill || nt-cast_x || cast_w3 ----
    fusedP_kernel<<<FILL_NB + CASTX_NB + CASTW_NB, 512, 0, stream>>>(
        src, dst, fillp, colu,
        x, (ushort*)S0, Wl1, Wr1, Wl2, Wr2, Wl3, Wr3, wlh, wll, wrh, wrl);

    const int agg_blocks = (NN * 64 + 255) / 256;

    // L1 gemm: ain=S0(xb) -> y=S1, z=S2
    gemm2_kernel<<<GEMM_NB, 512, 0, stream>>>((ushort*)S0, wlh, wll, wrh, wrl, bl1,
                                              (ushort*)S1, (ushort*)S2, NN);
    // L1 gather: h1 in S2
    gather_relu<<<agg_blocks, 256, 0, stream>>>((ushort*)S1, (ushort*)S2, fillp, colu, NN);
    // L2: A=S2 -> y=S1, z=S0; h2 in S0
    gemm2_kernel<<<GEMM_NB, 512, 0, stream>>>((ushort*)S2, wlh + 16384, wll + 16384,
                                              wrh + 16384, wrl + 16384, bl2,
                                              (ushort*)S1, (ushort*)S0, NN);
    gather_relu<<<agg_blocks, 256, 0, stream>>>((ushort*)S1, (ushort*)S0, fillp, colu, NN);
    // L3: A=S0 -> y=S1, z=S2; h3 in S2
    gemm2_kernel<<<GEMM_NB, 512, 0, stream>>>((ushort*)S0, wlh + 32768, wll + 32768,
                                              wrh + 32768, wrl + 32768, bl3,
                                              (ushort*)S1, (ushort*)S2, NN);
    gather_relu<<<agg_blocks, 256, 0, stream>>>((ushort*)S1, (ushort*)S2, fillp, colu, NN);

    // fused pool + head
    pool_head<<<NG, 256, 0, stream>>>((ushort*)S2, batch, NN, W1, b1, W2, b2, out);
}

// Round 31
// 239.801 us; speedup vs baseline: 1.0466x; 1.0466x over previous
//
#include <hip/hip_runtime.h>

#define NN 50000
#define NE 800000
#define D 128
#define NG 128
#define NGRP 8
#define GRPSZ 6250
#define FILL_NB 392                    // 49 slices x 8 groups
#define ESL ((NE + 48) / 49)
#define CAP 64
#define GEMM_NB 391

typedef __attribute__((ext_vector_type(8))) short bf16x8;
typedef __attribute__((ext_vector_type(4))) float f32x4;

static __device__ __forceinline__ ushort f2bf(float f) {
    uint x = __float_as_uint(f);
    x += 0x7fffu + ((x >> 16) & 1u);   // RNE
    return (ushort)(x >> 16);
}
static __device__ __forceinline__ float bf2f(ushort u) { return __uint_as_float((uint)u << 16); }
static __device__ __forceinline__ float blo16(uint u) { return __uint_as_float(u << 16); }
static __device__ __forceinline__ float bhi16(uint u) { return __uint_as_float(u & 0xffff0000u); }

// ---------------- fusedA: cast_x || cast_w3 ----------------
#define CASTX_NB 6250
#define CASTW_NB 192
__global__ __launch_bounds__(256) void fusedA_kernel(
    const float* __restrict__ x, ushort* __restrict__ xb,
    const float* __restrict__ Wl1, const float* __restrict__ Wr1,
    const float* __restrict__ Wl2, const float* __restrict__ Wr2,
    const float* __restrict__ Wl3, const float* __restrict__ Wr3,
    ushort* __restrict__ wlh, ushort* __restrict__ wll,
    ushort* __restrict__ wrh, ushort* __restrict__ wrl) {
    const int bid = blockIdx.x;
    if (bid < CASTX_NB) {
        int i = bid * 256 + threadIdx.x;
        int n = i >> 5, g = i & 31;
        float4 v = *reinterpret_cast<const float4*>(x + (size_t)n * D + g * 4);
        ushort4 o;
        o.x = f2bf(v.x); o.y = f2bf(v.y); o.z = f2bf(v.z); o.w = f2bf(v.w);
        *reinterpret_cast<ushort4*>(xb + (size_t)n * D + g * 4) = o;
    } else {
        int i = (bid - CASTX_NB) * 256 + threadIdx.x;
        int layer = i >> 14, j = i & 16383;
        int colg = j >> 7, k = j & 127;
        const float* Wl = (layer == 0) ? Wl1 : ((layer == 1) ? Wl2 : Wl3);
        const float* Wr = (layer == 0) ? Wr1 : ((layer == 1) ? Wr2 : Wr3);
        float vl = Wl[k * 128 + colg];
        float vr = Wr[k * 128 + colg];
        ushort hl = f2bf(vl), hr = f2bf(vr);
        wlh[i] = hl; wll[i] = f2bf(vl - bf2f(hl));
        wrh[i] = hr; wrl[i] = f2bf(vr - bf2f(hr));
    }
}

// ---------------- gemm2 body (2-term split-weight bf16 MFMA) ----------------
static __device__ __forceinline__ void gemm2_body(
    char* As, int rb,
    const ushort* __restrict__ ain,
    const ushort* __restrict__ wlh, const ushort* __restrict__ wll,
    const ushort* __restrict__ wrh, const ushort* __restrict__ wrl,
    const float* __restrict__ bl,
    ushort* __restrict__ y, ushort* __restrict__ z, int N) {
    const int tid = threadIdx.x;
    const int w = tid >> 6, lane = tid & 63;
    const int row0 = rb * 128;
    const int lrow = lane & 15, lk = lane >> 4;
    const int colg = w * 16 + lrow;

    bf16x8 ylh[4], yll[4], zrh[4], zrl[4];
#pragma unroll
    for (int kb = 0; kb < 4; ++kb) {
        int off = colg * 128 + kb * 32 + lk * 8;
        ylh[kb] = *reinterpret_cast<const bf16x8*>(wlh + off);
        yll[kb] = *reinterpret_cast<const bf16x8*>(wll + off);
        zrh[kb] = *reinterpret_cast<const bf16x8*>(wrh + off);
        zrl[kb] = *reinterpret_cast<const bf16x8*>(wrl + off);
    }
    const float bias = bl[colg];

    {   // stage 32 KB; source pre-swizzled (involution, 256B rows)
        const char* gbase = (const char*)ain + (size_t)row0 * 256;
#pragma unroll
        for (int i = 0; i < 4; ++i) {
            int Ld = i * 8192 + w * 1024 + lane * 16;
            int gs = Ld ^ (((Ld >> 8) & 7) << 4);
            __builtin_amdgcn_global_load_lds(
                (const uint*)(gbase + gs),
                (uint*)(As + i * 8192 + w * 1024), 16, 0, 0);
        }
    }
    __syncthreads();

#pragma unroll
    for (int mt = 0; mt < 8; ++mt) {
        const int ar = mt * 16 + lrow;
        const int swz = (ar & 7) << 4;
        const char* ap = As + ar * 256;
        bf16x8 ah[4];
#pragma unroll
        for (int kb = 0; kb < 4; ++kb) {
            int b_ = kb * 64 + lk * 16;
            ah[kb] = *reinterpret_cast<const bf16x8*>(ap + (b_ ^ swz));
        }
        f32x4 accy = {0.f, 0.f, 0.f, 0.f}, accz = {0.f, 0.f, 0.f, 0.f};
#pragma unroll
        for (int kb = 0; kb < 4; ++kb) {
            accy = __builtin_amdgcn_mfma_f32_16x16x32_bf16(ah[kb], ylh[kb], accy, 0, 0, 0);
            accy = __builtin_amdgcn_mfma_f32_16x16x32_bf16(ah[kb], yll[kb], accy, 0, 0, 0);
            accz = __builtin_amdgcn_mfma_f32_16x16x32_bf16(ah[kb], zrh[kb], accz, 0, 0, 0);
            accz = __builtin_amdgcn_mfma_f32_16x16x32_bf16(ah[kb], zrl[kb], accz, 0, 0, 0);
        }
#pragma unroll
        for (int r = 0; r < 4; ++r) {
            int rowg = row0 + mt * 16 + lk * 4 + r;
            if (rowg < N) {
                y[(size_t)rowg * D + colg] = f2bf(accy[r]);
                z[(size_t)rowg * D + colg] = f2bf(accz[r] + bias);
            }
        }
    }
}

__global__ __launch_bounds__(512, 4) void gemm2_kernel(
    const ushort* __restrict__ ain,
    const ushort* __restrict__ wlh, const ushort* __restrict__ wll,
    const ushort* __restrict__ wrh, const ushort* __restrict__ wrl,
    const float* __restrict__ bl,
    ushort* __restrict__ y, ushort* __restrict__ z, int N) {
    __shared__ char As[128 * 256];
    gemm2_body(As, blockIdx.x, ain, wlh, wll, wrh, wrl, bl, y, z, N);
}

// ---------------- fusedB: partitioned fixed-slot fill || gemm-L1 ----------------
__global__ __launch_bounds__(512, 4) void fusedB_kernel(
    const ushort* __restrict__ ain,
    const ushort* __restrict__ wlh, const ushort* __restrict__ wll,
    const ushort* __restrict__ wrh, const ushort* __restrict__ wrl,
    const float* __restrict__ bl,
    ushort* __restrict__ y, ushort* __restrict__ z,
    const int* __restrict__ src, const int* __restrict__ dst,
    int* __restrict__ fillp, ushort* __restrict__ colu, int N) {
    __shared__ char As[128 * 256];
    const int bid = blockIdx.x;
    if (bid < FILL_NB) {
        const int grp = bid & 7;
        const int slice = bid >> 3;
        const int dlo = grp * GRPSZ, dhi = dlo + GRPSZ;
        const int e0 = slice * ESL;
        const int e1 = min(e0 + ESL, NE);
        for (int e = e0 + (int)threadIdx.x; e < e1; e += 512) {
            int d = dst[e];
            if (d >= dlo && d < dhi) {
                int s = src[e];
                int pos = atomicAdd(&fillp[d], 1);
                if (pos < CAP) colu[d * CAP + pos] = (ushort)s;
            }
        }
    } else {
        gemm2_body(As, bid - FILL_NB, ain, wlh, wll, wrh, wrl, bl, y, z, N);
    }
}

// ---------------- gather: h = bf16(relu(mean_gather(y) + z)), in-place over z ----------------
__global__ __launch_bounds__(256) void gather_relu(
    const ushort* __restrict__ y, ushort* __restrict__ z,
    const int* __restrict__ deg, const ushort* __restrict__ colu, int N) {
    int wid = (blockIdx.x * 256 + threadIdx.x) >> 6;
    if (wid >= N) return;
    const int lane = threadIdx.x & 63;
    const int h = lane >> 5, li = lane & 31;
    const int dg = deg[wid];
    const int lo = wid * CAP;
    const int hi = lo + min(dg, CAP);
    float a0 = 0.f, a1 = 0.f, a2 = 0.f, a3 = 0.f;
    int e = lo + h;
    for (; e + 6 < hi; e += 8) {
        int s0 = colu[e], s1 = colu[e + 2], s2 = colu[e + 4], s3 = colu[e + 6];
        uint2 v0 = *reinterpret_cast<const uint2*>(y + (size_t)s0 * D + li * 4);
        uint2 v1 = *reinterpret_cast<const uint2*>(y + (size_t)s1 * D + li * 4);
        uint2 v2 = *reinterpret_cast<const uint2*>(y + (size_t)s2 * D + li * 4);
        uint2 v3 = *reinterpret_cast<const uint2*>(y + (size_t)s3 * D + li * 4);
        a0 += (blo16(v0.x) + blo16(v1.x)) + (blo16(v2.x) + blo16(v3.x));
        a1 += (bhi16(v0.x) + bhi16(v1.x)) + (bhi16(v2.x) + bhi16(v3.x));
        a2 += (blo16(v0.y) + blo16(v1.y)) + (blo16(v2.y) + blo16(v3.y));
        a3 += (bhi16(v0.y) + bhi16(v1.y)) + (bhi16(v2.y) + bhi16(v3.y));
    }
    for (; e < hi; e += 2) {
        int s = colu[e];
        uint2 v = *reinterpret_cast<const uint2*>(y + (size_t)s * D + li * 4);
        a0 += blo16(v.x); a1 += bhi16(v.x);
        a2 += blo16(v.y); a3 += bhi16(v.y);
    }
    a0 += __shfl_xor(a0, 32, 64);
    a1 += __shfl_xor(a1, 32, 64);
    a2 += __shfl_xor(a2, 32, 64);
    a3 += __shfl_xor(a3, 32, 64);
    if (h == 0) {
        float inv = 1.0f / fmaxf((float)dg, 1.0f);
        uint2 zv = *reinterpret_cast<const uint2*>(z + (size_t)wid * D + li * 4);
        float h0 = fmaxf(a0 * inv + blo16(zv.x), 0.f);
        float h1 = fmaxf(a1 * inv + bhi16(zv.x), 0.f);
        float h2 = fmaxf(a2 * inv + blo16(zv.y), 0.f);
        float h3 = fmaxf(a3 * inv + bhi16(zv.y), 0.f);
        uint2 o;
        o.x = (uint)f2bf(h0) | ((uint)f2bf(h1) << 16);
        o.y = (uint)f2bf(h2) | ((uint)f2bf(h3) << 16);
        *reinterpret_cast<uint2*>(z + (size_t)wid * D + li * 4) = o;
    }
}

// ---------------- fused pool+head ----------------
__global__ __launch_bounds__(256) void pool_head(
    const ushort* __restrict__ hbuf, const int* __restrict__ batch, int N,
    const float* __restrict__ W1, const float* __restrict__ b1,
    const float* __restrict__ W2, const float* __restrict__ b2,
    float* __restrict__ out) {
    __shared__ float part[4][128];
    __shared__ float gl[128];
    __shared__ float tl[128];
    __shared__ float lg[10];
    __shared__ float red[2];
    const int b = blockIdx.x;
    const int tid = threadIdx.x;
    const int wv = tid >> 6, lane = tid & 63;
    const int cb = lane * 2;

    int lo = 0, r = N;
    while (lo < r) { int m = (lo + r) >> 1; if (batch[m] < b) lo = m + 1; else r = m; }
    int hi = lo; r = N;
    while (hi < r) { int m = (hi + r) >> 1; if (batch[m] < b + 1) hi = m + 1; else r = m; }

    float a0 = 0.f, a1 = 0.f;
    for (int n = lo + wv; n < hi; n += 4) {
        uint v = *reinterpret_cast<const uint*>(hbuf + (size_t)n * D + cb);
        a0 += blo16(v); a1 += bhi16(v);
    }
    part[wv][cb] = a0;
    part[wv][cb + 1] = a1;
    __syncthreads();

    const int j = tid & 127;
    if (tid < 128) {
        float c = fmaxf((float)(hi - lo), 1.0f);
        gl[j] = (part[0][j] + part[1][j] + part[2][j] + part[3][j]) / c;
    }
    __syncthreads();

    if (tid < 128) {
        float t = b1[j];
        for (int k = 0; k < 128; ++k) t += gl[k] * W1[k * 128 + j];
        tl[j] = fmaxf(t, 0.0f);
    }
    __syncthreads();

    if (tid < 10) {
        float acc = b2[tid];
        for (int k = 0; k < 128; ++k) acc += tl[k] * W2[k * 10 + tid];
        lg[tid] = acc;
    }
    __syncthreads();

    if (tid == 0) {
        float m = lg[0];
        for (int q = 1; q < 10; ++q) m = fmaxf(m, lg[q]);
        float s = 0.0f;
        for (int q = 0; q < 10; ++q) s += expf(lg[q] - m);
        red[0] = m;
        red[1] = logf(s);
    }
    __syncthreads();

    if (tid < 10) out[b * 10 + tid] = lg[tid] - red[0] - red[1];
}

extern "C" void kernel_launch(void* const* d_in, const int* in_sizes, int n_in,
                              void* d_out, int out_size, void* d_ws, size_t ws_size,
                              hipStream_t stream) {
    const float* x    = (const float*)d_in[0];
    const int*   ei   = (const int*)d_in[1];
    const int*   src  = ei;
    const int*   dst  = ei + NE;
    const int*   batch = (const int*)d_in[2];
    const float* Wl1 = (const float*)d_in[3];
    const float* bl1 = (const float*)d_in[4];
    const float* Wr1 = (const float*)d_in[5];
    const float* Wl2 = (const float*)d_in[6];
    const float* bl2 = (const float*)d_in[7];
    const float* Wr2 = (const float*)d_in[8];
    const float* Wl3 = (const float*)d_in[9];
    const float* bl3 = (const float*)d_in[10];
    const float* Wr3 = (const float*)d_in[11];
    const float* W1  = (const float*)d_in[12];
    const float* b1  = (const float*)d_in[13];
    const float* W2  = (const float*)d_in[14];
    const float* b2  = (const float*)d_in[15];
    float* out = (float*)d_out;

    char* p = (char*)d_ws;
    char* S0 = p; p += 12800000;     // x/h bf16 [N][128]
    char* S1 = p; p += 12800000;     // y bf16
    char* S2 = p; p += 12800000;     // z / h bf16 (in place)
    ushort* wlh = (ushort*)p; p += 3 * 32768;
    ushort* wll = (ushort*)p; p += 3 * 32768;
    ushort* wrh = (ushort*)p; p += 3 * 32768;
    ushort* wrl = (ushort*)p; p += 3 * 32768;
    int* fillp   = (int*)p;   p += 200000;
    ushort* colu = (ushort*)p; p += NN * CAP * 2;   // 6.4 MB
    // ~46 MB total

    hipMemsetAsync(fillp, 0, (size_t)NN * 4, stream);

    fusedA_kernel<<<CASTX_NB + CASTW_NB, 256, 0, stream>>>(
        x, (ushort*)S0, Wl1, Wr1, Wl2, Wr2, Wl3, Wr3, wlh, wll, wrh, wrl);

    const int agg_blocks = (NN * 64 + 255) / 256;

    // ---- fusedB: partitioned fixed-slot fill || gemm2-L1 ----
    fusedB_kernel<<<FILL_NB + GEMM_NB, 512, 0, stream>>>(
        (ushort*)S0, wlh, wll, wrh, wrl, bl1, (ushort*)S1, (ushort*)S2,
        src, dst, fillp, colu, NN);

    // L1 gather: h1 in S2
    gather_relu<<<agg_blocks, 256, 0, stream>>>((ushort*)S1, (ushort*)S2, fillp, colu, NN);
    // L2: A=S2 -> y=S1, z=S0; h2 in S0
    gemm2_kernel<<<GEMM_NB, 512, 0, stream>>>((ushort*)S2, wlh + 16384, wll + 16384,
                                              wrh + 16384, wrl + 16384, bl2,
                                              (ushort*)S1, (ushort*)S0, NN);
    gather_relu<<<agg_blocks, 256, 0, stream>>>((ushort*)S1, (ushort*)S0, fillp, colu, NN);
    // L3: A=S0 -> y=S1, z=S2; h3 in S2
    gemm2_kernel<<<GEMM_NB, 512, 0, stream>>>((ushort*)S0, wlh + 32768, wll + 32768,
                                              wrh + 32768, wrl + 32768, bl3,
                                              (ushort*)S1, (ushort*)S2, NN);
    gather_relu<<<agg_blocks, 256, 0, stream>>>((ushort*)S1, (ushort*)S2, fillp, colu, NN);

    // fused pool + head
    pool_head<<<NG, 256, 0, stream>>>((ushort*)S2, batch, NN, W1, b1, W2, b2, out);
}